// Round 16
// baseline (531.398 us; speedup 1.0000x reference)
//
#include <hip/hip_runtime.h>

#define B_  8
#define P_  21
#define H_  32
#define W_  32

typedef float f32x4 __attribute__((ext_vector_type(4)));
typedef _Float16 f16x8 __attribute__((ext_vector_type(8)));
typedef _Float16 f16x4 __attribute__((ext_vector_type(4)));
typedef _Float16 f16x2v __attribute__((ext_vector_type(2)));

// async global->LDS, 16B per lane; LDS dst must be wave-uniform base (HW adds lane*16)
__device__ __forceinline__ void gload_lds16(const _Float16* g, _Float16* l) {
  __builtin_amdgcn_global_load_lds(
      (const __attribute__((address_space(1))) void*)g,
      (__attribute__((address_space(3))) void*)l, 16, 0, 0);
}

// ---------------------------------------------------------------- CSR build structs
struct CsrParams {
  const int*   row[4];
  const int*   col[4];
  const float* val[4];
  int*   cnt[4];
  int*   rowptr[4];
  int*   colsout[4];
  float* valsout[4];
  int    nnz[4];
  int    V[4];
};

struct BsplitParams {
  const float* wp[4];
  int K[4], N[4], off[4];
  _Float16* b0;
  _Float16* b1;
};

// ---------------------------------------------------------------- K1: zero (60 blks) || sample (168 blks)
__global__ __launch_bounds__(256) void k1_zero_sample(
    int* zp, int zn,
    const float* __restrict__ uv,
    const float* __restrict__ feat,
    float* __restrict__ xs) {
  int bid = blockIdx.x;
  if (bid < 60) {
    int i = bid * 256 + threadIdx.x;
    if (i < zn) zp[i] = 0;
    return;
  }
  int bp = bid - 60;                 // b*21+p
  int b  = bp / P_;
  float u0 = uv[bp * 2 + 0], u1 = uv[bp * 2 + 1];
  float gx = fminf(fmaxf((u0 - 0.5f) * 2.0f, -1.0f), 1.0f);
  float gy = fminf(fmaxf((u1 - 0.5f) * 2.0f, -1.0f), 1.0f);
  float fx = (gx + 1.0f) * 0.5f * (W_ - 1);
  float fy = (gy + 1.0f) * 0.5f * (H_ - 1);
  float x0f = floorf(fx), y0f = floorf(fy);
  float wx = fx - x0f, wy = fy - y0f;
  int x0 = (int)x0f, y0 = (int)y0f;
  int x0i = min(max(x0, 0), W_ - 1), x1i = min(max(x0 + 1, 0), W_ - 1);
  int y0i = min(max(y0, 0), H_ - 1), y1i = min(max(y0 + 1, 0), H_ - 1);
  float w00 = (1.f - wy) * (1.f - wx), w01 = (1.f - wy) * wx;
  float w10 = wy * (1.f - wx),        w11 = wy * wx;
  for (int c = threadIdx.x; c < 512; c += blockDim.x) {
    const float* fb = feat + ((size_t)(b * 512 + c)) * (H_ * W_);
    float v = fb[y0i * W_ + x0i] * w00 + fb[y0i * W_ + x1i] * w01 +
              fb[y1i * W_ + x0i] * w10 + fb[y1i * W_ + x1i] * w11;
    xs[(size_t)bp * 512 + c] = v;
  }
}

// ---------------------------------------------------------------- K2: count (384 blks) || upsample (4096 blks)
__global__ __launch_bounds__(256) void k2_count_upsample(
    CsrParams p,
    const float* __restrict__ up,
    const float* __restrict__ xs,
    float* __restrict__ xu) {
  int bid = blockIdx.x;
  if (bid < 384) {
    int l = bid / 96;
    int k = (bid - l * 96) * 256 + threadIdx.x;
    if (k < p.nnz[l]) atomicAdd(&p.cnt[l][p.row[l][k]], 1);
    return;
  }
  int b2 = bid - 384;                // [0, 4096)
  int b = b2 >> 9, v = b2 & 511;
  int c2 = threadIdx.x << 1;         // 256 thr * 2 ch = 512
  float2 acc = make_float2(0.f, 0.f);
  for (int q = 0; q < P_; ++q) {
    float u = up[v * P_ + q];
    const float2 xv = *(const float2*)&xs[((size_t)(b * P_ + q)) * 512 + c2];
    acc.x = fmaf(u, xv.x, acc.x);
    acc.y = fmaf(u, xv.y, acc.y);
  }
  *(float2*)&xu[((size_t)(b * 512 + v)) * 512 + c2] = acc;
}

// ---------------------------------------------------------------- K3: scan (4 blks) || bsplit (rest)
__global__ __launch_bounds__(256) void k3_scan_bsplit(CsrParams p, BsplitParams bp) {
  int bid = blockIdx.x;
  if (bid < 4) {
    int l = bid;
    int V = p.V[l];
    int* cnt = p.cnt[l];
    int* rp  = p.rowptr[l];
    int t = threadIdx.x;
    int chunk = V / 256;
    int base = t * chunk;
    int s = 0;
    for (int i = 0; i < chunk; ++i) s += cnt[base + i];
    __shared__ int sm[256];
    sm[t] = s;
    __syncthreads();
    for (int off = 1; off < 256; off <<= 1) {
      int v = (t >= off) ? sm[t - off] : 0;
      __syncthreads();
      sm[t] += v;
      __syncthreads();
    }
    int run = sm[t] - s;
    for (int i = 0; i < chunk; ++i) {
      int c = cnt[base + i];
      rp[base + i]  = run;
      cnt[base + i] = run;
      run += c;
    }
    if (t == 255) rp[V] = run;
    return;
  }
  int idx = (bid - 4) * 256 + threadIdx.x;
  #pragma unroll
  for (int t = 0; t < 4; ++t) {
    int sz = bp.N[t] * bp.K[t];
    if (idx < sz) {
      int K = bp.K[t];
      int n = idx / K, k = idx - n * K;
      float v = bp.wp[t][(size_t)k * bp.N[t] + n];
      _Float16 h0 = (_Float16)v;
      float r = (v - (float)h0) * 2048.0f;
      int ks = ((((k >> 3) ^ (n & 7)) << 3) | (k & 7));   // chunk-XOR swizzle
      bp.b0[bp.off[t] + (size_t)n * K + ks] = h0;
      bp.b1[bp.off[t] + (size_t)n * K + ks] = (_Float16)r;
      return;
    }
    idx -= sz;
  }
}

// ---------------------------------------------------------------- K4: fill
__global__ void fill_kernel(CsrParams p) {
  int l = blockIdx.y;
  int k = blockIdx.x * 256 + threadIdx.x;
  if (k < p.nnz[l]) {
    int r = p.row[l][k];
    int pos = atomicAdd(&p.cnt[l][r], 1);
    p.colsout[l][pos] = p.col[l][k];
    p.valsout[l][pos] = p.val[l][k];
  }
}

// ---------------------------------------------------------------- fused pool->LDS->dw->split per (batch, ch-chunk)
// Phase A: pooled[V][CH] computed into LDS (CSR gather from x; per-block x
// slice is 32-64KB -> L1/L2-hot). Phase B: 9-tap dw reads LDS ONLY, f16x2
// split, swizzled A-plane store. Kills the 1.1GB pooled global round-trip.
// STR chosen for bank spread: CH=8->10, CH=4->7 (coprime-ish), CH=2->3.
template <int CH, int V>
__global__ __launch_bounds__(256) void pooldw_lds_kernel(
    const float* __restrict__ x,      // [B][Vin][Cin]
    const int* __restrict__ rowptr,
    const int* __restrict__ cols,
    const float* __restrict__ vals,
    const int* __restrict__ sidx,     // [V][9]
    const float* __restrict__ wd,     // [9][Cin]
    _Float16* __restrict__ a0o,
    _Float16* __restrict__ a1o,
    int Vin, int Cin) {
  constexpr int STR = (CH == 8) ? 10 : (CH == 4 ? 7 : 3);
  __shared__ float pooled[V * STR];
  const int bid = blockIdx.x;
  const int b   = bid & 7;            // XCD-affine batch
  const int c0  = (bid >> 3) * CH;    // channel chunk base
  const int t   = threadIdx.x;
  const int R   = V >> 8;             // rows per thread
  const float* xb = x + (size_t)b * Vin * Cin + c0;

  // ---- Phase A: pool into LDS
  for (int i = 0; i < R; ++i) {
    int n = t + (i << 8);
    int j0 = rowptr[n], j1 = rowptr[n + 1];
    float acc[CH];
    #pragma unroll
    for (int c = 0; c < CH; ++c) acc[c] = 0.f;
    for (int j = j0; j < j1; ++j) {
      float v = vals[j];
      const float* xr = xb + (size_t)cols[j] * Cin;
      if constexpr (CH == 8) {
        float4 x0 = *(const float4*)xr;
        float4 x1 = *(const float4*)(xr + 4);
        acc[0] = fmaf(v, x0.x, acc[0]); acc[1] = fmaf(v, x0.y, acc[1]);
        acc[2] = fmaf(v, x0.z, acc[2]); acc[3] = fmaf(v, x0.w, acc[3]);
        acc[4] = fmaf(v, x1.x, acc[4]); acc[5] = fmaf(v, x1.y, acc[5]);
        acc[6] = fmaf(v, x1.z, acc[6]); acc[7] = fmaf(v, x1.w, acc[7]);
      } else if constexpr (CH == 4) {
        float4 x0 = *(const float4*)xr;
        acc[0] = fmaf(v, x0.x, acc[0]); acc[1] = fmaf(v, x0.y, acc[1]);
        acc[2] = fmaf(v, x0.z, acc[2]); acc[3] = fmaf(v, x0.w, acc[3]);
      } else {
        float2 x0 = *(const float2*)xr;
        acc[0] = fmaf(v, x0.x, acc[0]); acc[1] = fmaf(v, x0.y, acc[1]);
      }
    }
    float* pr = &pooled[n * STR];
    #pragma unroll
    for (int c = 0; c < CH; ++c) pr[c] = acc[c];
  }
  __syncthreads();

  // ---- Phase B: dw from LDS + f16x2 split + swizzled store
  for (int i = 0; i < R; ++i) {
    int n = t + (i << 8);
    float acc[CH];
    #pragma unroll
    for (int c = 0; c < CH; ++c) acc[c] = 0.f;
    #pragma unroll
    for (int s = 0; s < 9; ++s) {
      int r = sidx[n * 9 + s];
      const float* pr = &pooled[r * STR];
      const float* wr = wd + s * Cin + c0;      // uniform -> s_load
      #pragma unroll
      for (int c = 0; c < CH; ++c)
        acc[c] = fmaf(wr[c], pr[c], acc[c]);
    }
    size_t m = (size_t)b * V + n;
    _Float16 hi[CH], lo[CH];
    #pragma unroll
    for (int c = 0; c < CH; ++c) {
      _Float16 h0 = (_Float16)acc[c];
      float rr = (acc[c] - (float)h0) * 2048.0f;  // exact pow2; lo stays normal
      hi[c] = h0; lo[c] = (_Float16)rr;
    }
    const int cc  = c0 >> 3;
    const int o   = c0 & 7;
    const int pos = (((cc ^ (n & 7)) << 3) | o);  // chunk-XOR swizzle
    _Float16* p0 = &a0o[m * Cin + pos];
    _Float16* p1 = &a1o[m * Cin + pos];
    if constexpr (CH == 8) {
      *(f16x8*)p0 = *(f16x8*)hi;
      *(f16x8*)p1 = *(f16x8*)lo;
    } else if constexpr (CH == 4) {
      *(f16x4*)p0 = *(f16x4*)hi;
      *(f16x4*)p1 = *(f16x4*)lo;
    } else {
      *(f16x2v*)p0 = *(f16x2v*)hi;
      *(f16x2v*)p1 = *(f16x2v*)lo;
    }
  }
}

// ---------------------------------------------------------------- f16x2-split MFMA GEMM + bias + relu (batch-affine)
// BM=128, BN=64, BK=64; 2x2 waves, wave tile 64x32, mfma 16x16x32.
// Staging via global_load_lds (16B/lane, linear LDS); operands pre-swizzled
// in global (chunk^(row&7)), reads apply the same XOR. LDS 48KB -> 3 blk/CU.
__global__ __launch_bounds__(256) void gemm_f16x2(
    const _Float16* __restrict__ A0, const _Float16* __restrict__ A1,
    const _Float16* __restrict__ Bt0, const _Float16* __restrict__ Bt1,
    const float* __restrict__ bias, float* __restrict__ C,
    int M, int N, int K) {
  __shared__ _Float16 As[2][128 * 64];      // linear; halves index = chunk*8
  __shared__ _Float16 Bs[2][64 * 64];
  const int tid = threadIdx.x;
  const int bx = blockIdx.x;
  const int xr_ = (bx & 7) * (gridDim.x >> 3) + (bx >> 3);   // batch-affine remap
  const int m0 = xr_ * 128, n0 = blockIdx.y * 64;
  const int wid = tid >> 6, lane = tid & 63;
  const int wr = wid >> 1, wc = wid & 1;
  const int lo = lane & 15, hi = lane >> 4;

  f32x4 accM[4][2], accC[4][2];
  #pragma unroll
  for (int mi = 0; mi < 4; ++mi)
    #pragma unroll
    for (int nj = 0; nj < 2; ++nj) {
      accM[mi][nj] = (f32x4){0.f, 0.f, 0.f, 0.f};
      accC[mi][nj] = (f32x4){0.f, 0.f, 0.f, 0.f};
    }

  const _Float16* gA[2] = {A0, A1};
  const _Float16* gB[2] = {Bt0, Bt1};

  for (int k0 = 0; k0 < K; k0 += 64) {
    #pragma unroll
    for (int p = 0; p < 2; ++p) {
      #pragma unroll
      for (int i = 0; i < 4; ++i) {          // A plane: 1024 16B chunks
        int c = tid + 256 * i;
        int r = c >> 3, k8 = (c & 7) << 3;
        gload_lds16(gA[p] + (size_t)(m0 + r) * K + k0 + k8,
                    &As[p][(c & ~63) * 8]);  // wave-uniform base; HW adds lane*16B
      }
      #pragma unroll
      for (int i = 0; i < 2; ++i) {          // B plane: 512 chunks
        int c = tid + 256 * i;
        int r = c >> 3, k8 = (c & 7) << 3;
        gload_lds16(gB[p] + (size_t)(n0 + r) * K + k0 + k8,
                    &Bs[p][(c & ~63) * 8]);
      }
    }
    __syncthreads();                          // compiler drains vmcnt before barrier
    #pragma unroll
    for (int s = 0; s < 2; ++s) {
      const int cl = s * 4 + hi;              // local chunk 0..7 (kk = cl*8)
      f16x8 af[4][2], bf[2][2];
      #pragma unroll
      for (int mi = 0; mi < 4; ++mi) {
        const int rr = wr * 64 + mi * 16 + lo;
        const int ko = (cl ^ (rr & 7)) << 3;  // un-swizzle on read
        af[mi][0] = *(const f16x8*)&As[0][rr * 64 + ko];
        af[mi][1] = *(const f16x8*)&As[1][rr * 64 + ko];
      }
      #pragma unroll
      for (int nj = 0; nj < 2; ++nj) {
        const int rb = wc * 32 + nj * 16 + lo;
        const int ko = (cl ^ (rb & 7)) << 3;
        bf[nj][0] = *(const f16x8*)&Bs[0][rb * 64 + ko];
        bf[nj][1] = *(const f16x8*)&Bs[1][rb * 64 + ko];
      }
      #pragma unroll
      for (int mi = 0; mi < 4; ++mi)
        #pragma unroll
        for (int nj = 0; nj < 2; ++nj) {
          accM[mi][nj] = __builtin_amdgcn_mfma_f32_16x16x32_f16(
              af[mi][0], bf[nj][0], accM[mi][nj], 0, 0, 0);
          accC[mi][nj] = __builtin_amdgcn_mfma_f32_16x16x32_f16(
              af[mi][0], bf[nj][1], accC[mi][nj], 0, 0, 0);
          accC[mi][nj] = __builtin_amdgcn_mfma_f32_16x16x32_f16(
              af[mi][1], bf[nj][0], accC[mi][nj], 0, 0, 0);
        }
    }
    __syncthreads();
  }

  const float INV = 1.0f / 2048.0f;
  #pragma unroll
  for (int mi = 0; mi < 4; ++mi)
    #pragma unroll
    for (int nj = 0; nj < 2; ++nj) {
      int col = n0 + wc * 32 + nj * 16 + lo;
      float bv = bias[col];
      #pragma unroll
      for (int r = 0; r < 4; ++r) {
        int row = m0 + wr * 64 + mi * 16 + hi * 4 + r;
        float v = accM[mi][nj][r] + accC[mi][nj][r] * INV + bv;
        v = fmaxf(v, 0.f);
        C[(size_t)row * N + col] = v;
      }
    }
}

// ---------------------------------------------------------------- fused head: dw (Cin=64, lane=channel) + 64x3 proj
__global__ __launch_bounds__(256) void head_fused_kernel(
    const float* __restrict__ x,      // [8][8192][64]
    const int* __restrict__ sidx,     // [8192][9]
    const float* __restrict__ wdh,    // [9][64]
    const float* __restrict__ wph,    // [64][3]
    const float* __restrict__ bh,
    float* __restrict__ out) {        // [8][8192][3]
  const int bid  = blockIdx.x;
  const int b    = bid & 7;           // XCD-affine batch
  const int wid  = threadIdx.x >> 6;
  const int lane = threadIdx.x & 63;
  const int n    = (bid >> 3) * 4 + wid;
  const float* xb = x + (size_t)b * 8192 * 64 + lane;

  int idx[9];
  #pragma unroll
  for (int s = 0; s < 9; ++s) idx[s] = sidx[n * 9 + s];

  float acc = 0.f;
  #pragma unroll
  for (int s = 0; s < 9; ++s)
    acc = fmaf(wdh[s * 64 + lane], xb[(size_t)idx[s] * 64], acc);

  float a0 = acc * wph[lane * 3 + 0];
  float a1 = acc * wph[lane * 3 + 1];
  float a2 = acc * wph[lane * 3 + 2];
  for (int off = 32; off > 0; off >>= 1) {
    a0 += __shfl_down(a0, off);
    a1 += __shfl_down(a1, off);
    a2 += __shfl_down(a2, off);
  }
  if (lane == 0) {
    size_t row = (size_t)b * 8192 + n;
    out[row * 3 + 0] = a0 + bh[0];
    out[row * 3 + 1] = a1 + bh[1];
    out[row * 3 + 2] = a2 + bh[2];
  }
}

// ---------------------------------------------------------------- launch
extern "C" void kernel_launch(void* const* d_in, const int* in_sizes, int n_in,
                              void* d_out, int out_size, void* d_ws, size_t ws_size,
                              hipStream_t stream) {
  const float* uv   = (const float*)d_in[0];
  const float* feat = (const float*)d_in[1];
  const float* up   = (const float*)d_in[2];
  const int* sArr[4] = {(const int*)d_in[3], (const int*)d_in[4],
                        (const int*)d_in[5], (const int*)d_in[6]};

  // workspace layout
  const size_t SLAB = 8ull * 2048 * 512;            // 8,388,608 elements
  float* Wf = (float*)d_ws;
  float* S0 = Wf;                                   // fp32 slab (x / gemm out); live < 4.2M floats
  float* S1 = Wf + SLAB;                            // (now unused spare)
  _Float16* A0 = (_Float16*)(S1 + SLAB);            // dw hi plane (pre-swizzled)
  _Float16* A1 = A0 + SLAB;                         // dw lo plane
  _Float16* Bt0all = (_Float16*)(S0 + 4500000);     // dead upper part of S0
  _Float16* Bt1all = Bt0all + 434176;
  float* xs = (float*)(A1 + SLAB);                  // B*P*512 floats
  int* ib = (int*)(xs + (size_t)B_ * P_ * 512);

  int Vt[4] = {1024, 2048, 4096, 8192};
  int NZ[4] = {3072, 6144, 12288, 24576};
  int* cnt[4]; int* rp[4]; int* co[4]; float* va[4];
  {
    int* pc = ib;
    for (int t = 0; t < 4; ++t) { cnt[t] = pc; pc += Vt[t]; }          // 15360 ints
    for (int t = 0; t < 4; ++t) { rp[t] = pc; pc += Vt[t] + 1; }
    for (int t = 0; t < 4; ++t) { co[t] = pc; pc += NZ[t]; }
    float* pv = (float*)pc;
    for (int t = 0; t < 4; ++t) { va[t] = pv; pv += NZ[t]; }
  }

  CsrParams cp;
  for (int t = 0; t < 4; ++t) {
    int i = 3 - t;
    cp.row[t] = (const int*)d_in[7 + 3 * i];
    cp.col[t] = (const int*)d_in[8 + 3 * i];
    cp.val[t] = (const float*)d_in[9 + 3 * i];
    cp.cnt[t] = cnt[t]; cp.rowptr[t] = rp[t];
    cp.colsout[t] = co[t]; cp.valsout[t] = va[t];
    cp.nnz[t] = NZ[t]; cp.V[t] = Vt[t];
  }

  struct Stg { int Vin, Vout, Cin, Cout; const int* s; const float *wd, *wp, *bias; };
  Stg st[4] = {
    {512, 1024, 512, 512, sArr[3], (const float*)d_in[19], (const float*)d_in[20], (const float*)d_in[21]},
    {1024, 2048, 512, 256, sArr[2], (const float*)d_in[22], (const float*)d_in[23], (const float*)d_in[24]},
    {2048, 4096, 256, 128, sArr[1], (const float*)d_in[25], (const float*)d_in[26], (const float*)d_in[27]},
    {4096, 8192, 128, 64, sArr[0], (const float*)d_in[28], (const float*)d_in[29], (const float*)d_in[30]},
  };

  BsplitParams bp;
  int boff = 0;
  for (int t = 0; t < 4; ++t) {
    bp.wp[t] = st[t].wp;
    bp.K[t] = st[t].Cin; bp.N[t] = st[t].Cout;
    bp.off[t] = boff;
    boff += st[t].Cin * st[t].Cout;           // 434176 total
  }
  bp.b0 = Bt0all; bp.b1 = Bt1all;
  int bsplit_blocks = (boff + 255) / 256;     // 1696

  // front matter: 4 merged kernels (3 independent chains interleaved)
  k1_zero_sample<<<60 + B_ * P_, 256, 0, stream>>>(ib, 15360, uv, feat, xs);
  k2_count_upsample<<<384 + 512 * B_, 256, 0, stream>>>(cp, up, xs, S0);
  k3_scan_bsplit<<<4 + bsplit_blocks, 256, 0, stream>>>(cp, bp);
  fill_kernel<<<dim3(96, 4), 256, 0, stream>>>(cp);

  for (int t = 0; t < 4; ++t) {
    // fused pool(LDS)+dw+split: grid = 8 batches x (Cin/CH) chunks = 512
    if (t == 0)
      pooldw_lds_kernel<8, 1024><<<512, 256, 0, stream>>>(
          S0, rp[0], co[0], va[0], st[0].s, st[0].wd, A0, A1, st[0].Vin, st[0].Cin);
    else if (t == 1)
      pooldw_lds_kernel<8, 2048><<<512, 256, 0, stream>>>(
          S0, rp[1], co[1], va[1], st[1].s, st[1].wd, A0, A1, st[1].Vin, st[1].Cin);
    else if (t == 2)
      pooldw_lds_kernel<4, 4096><<<512, 256, 0, stream>>>(
          S0, rp[2], co[2], va[2], st[2].s, st[2].wd, A0, A1, st[2].Vin, st[2].Cin);
    else
      pooldw_lds_kernel<2, 8192><<<512, 256, 0, stream>>>(
          S0, rp[3], co[3], va[3], st[3].s, st[3].wd, A0, A1, st[3].Vin, st[3].Cin);

    int M = B_ * st[t].Vout;
    gemm_f16x2<<<dim3(M / 128, st[t].Cout / 64), 256, 0, stream>>>(
        A0, A1, Bt0all + bp.off[t], Bt1all + bp.off[t],
        st[t].bias, S0, M, st[t].Cout, st[t].Cin);
  }

  // fused head: dw (K=64) + 64x3 projection, one launch
  head_fused_kernel<<<8 * (8192 / 4), 256, 0, stream>>>(
      S0, sArr[0], (const float*)d_in[31], (const float*)d_in[32],
      (const float*)d_in[33], (float*)d_out);
}

// Round 17
// 265.824 us; speedup vs baseline: 1.9991x; 1.9991x over previous
//
#include <hip/hip_runtime.h>

#define B_  8
#define P_  21
#define H_  32
#define W_  32

typedef float f32x4 __attribute__((ext_vector_type(4)));
typedef _Float16 f16x8 __attribute__((ext_vector_type(8)));

// async global->LDS, 16B per lane; LDS dst must be wave-uniform base (HW adds lane*16)
__device__ __forceinline__ void gload_lds16(const _Float16* g, _Float16* l) {
  __builtin_amdgcn_global_load_lds(
      (const __attribute__((address_space(1))) void*)g,
      (__attribute__((address_space(3))) void*)l, 16, 0, 0);
}

// ---------------------------------------------------------------- CSR build structs
struct CsrParams {
  const int*   row[4];
  const int*   col[4];
  const float* val[4];
  int*   cnt[4];
  int*   rowptr[4];
  int*   colsout[4];
  float* valsout[4];
  int    nnz[4];
  int    V[4];
};

struct BsplitParams {
  const float* wp[4];
  int K[4], N[4], off[4];
  _Float16* b0;
  _Float16* b1;
};

// ---------------------------------------------------------------- K1: zero (60 blks) || sample (168 blks)
__global__ __launch_bounds__(256) void k1_zero_sample(
    int* zp, int zn,
    const float* __restrict__ uv,
    const float* __restrict__ feat,
    float* __restrict__ xs) {
  int bid = blockIdx.x;
  if (bid < 60) {
    int i = bid * 256 + threadIdx.x;
    if (i < zn) zp[i] = 0;
    return;
  }
  int bp = bid - 60;                 // b*21+p
  int b  = bp / P_;
  float u0 = uv[bp * 2 + 0], u1 = uv[bp * 2 + 1];
  float gx = fminf(fmaxf((u0 - 0.5f) * 2.0f, -1.0f), 1.0f);
  float gy = fminf(fmaxf((u1 - 0.5f) * 2.0f, -1.0f), 1.0f);
  float fx = (gx + 1.0f) * 0.5f * (W_ - 1);
  float fy = (gy + 1.0f) * 0.5f * (H_ - 1);
  float x0f = floorf(fx), y0f = floorf(fy);
  float wx = fx - x0f, wy = fy - y0f;
  int x0 = (int)x0f, y0 = (int)y0f;
  int x0i = min(max(x0, 0), W_ - 1), x1i = min(max(x0 + 1, 0), W_ - 1);
  int y0i = min(max(y0, 0), H_ - 1), y1i = min(max(y0 + 1, 0), H_ - 1);
  float w00 = (1.f - wy) * (1.f - wx), w01 = (1.f - wy) * wx;
  float w10 = wy * (1.f - wx),        w11 = wy * wx;
  for (int c = threadIdx.x; c < 512; c += blockDim.x) {
    const float* fb = feat + ((size_t)(b * 512 + c)) * (H_ * W_);
    float v = fb[y0i * W_ + x0i] * w00 + fb[y0i * W_ + x1i] * w01 +
              fb[y1i * W_ + x0i] * w10 + fb[y1i * W_ + x1i] * w11;
    xs[(size_t)bp * 512 + c] = v;
  }
}

// ---------------------------------------------------------------- K2: count (384 blks) || upsample (4096 blks)
__global__ __launch_bounds__(256) void k2_count_upsample(
    CsrParams p,
    const float* __restrict__ up,
    const float* __restrict__ xs,
    float* __restrict__ xu) {
  int bid = blockIdx.x;
  if (bid < 384) {
    int l = bid / 96;
    int k = (bid - l * 96) * 256 + threadIdx.x;
    if (k < p.nnz[l]) atomicAdd(&p.cnt[l][p.row[l][k]], 1);
    return;
  }
  int b2 = bid - 384;                // [0, 4096)
  int b = b2 >> 9, v = b2 & 511;
  int c2 = threadIdx.x << 1;         // 256 thr * 2 ch = 512
  float2 acc = make_float2(0.f, 0.f);
  for (int q = 0; q < P_; ++q) {
    float u = up[v * P_ + q];
    const float2 xv = *(const float2*)&xs[((size_t)(b * P_ + q)) * 512 + c2];
    acc.x = fmaf(u, xv.x, acc.x);
    acc.y = fmaf(u, xv.y, acc.y);
  }
  *(float2*)&xu[((size_t)(b * 512 + v)) * 512 + c2] = acc;
}

// ---------------------------------------------------------------- K3: scan (4 blks) || bsplit (rest)
__global__ __launch_bounds__(256) void k3_scan_bsplit(CsrParams p, BsplitParams bp) {
  int bid = blockIdx.x;
  if (bid < 4) {
    int l = bid;
    int V = p.V[l];
    int* cnt = p.cnt[l];
    int* rp  = p.rowptr[l];
    int t = threadIdx.x;
    int chunk = V / 256;
    int base = t * chunk;
    int s = 0;
    for (int i = 0; i < chunk; ++i) s += cnt[base + i];
    __shared__ int sm[256];
    sm[t] = s;
    __syncthreads();
    for (int off = 1; off < 256; off <<= 1) {
      int v = (t >= off) ? sm[t - off] : 0;
      __syncthreads();
      sm[t] += v;
      __syncthreads();
    }
    int run = sm[t] - s;
    for (int i = 0; i < chunk; ++i) {
      int c = cnt[base + i];
      rp[base + i]  = run;
      cnt[base + i] = run;
      run += c;
    }
    if (t == 255) rp[V] = run;
    return;
  }
  int idx = (bid - 4) * 256 + threadIdx.x;
  #pragma unroll
  for (int t = 0; t < 4; ++t) {
    int sz = bp.N[t] * bp.K[t];
    if (idx < sz) {
      int K = bp.K[t];
      int n = idx / K, k = idx - n * K;
      float v = bp.wp[t][(size_t)k * bp.N[t] + n];
      _Float16 h0 = (_Float16)v;
      float r = (v - (float)h0) * 2048.0f;
      int ks = ((((k >> 3) ^ (n & 7)) << 3) | (k & 7));   // chunk-XOR swizzle
      bp.b0[bp.off[t] + (size_t)n * K + ks] = h0;
      bp.b1[bp.off[t] + (size_t)n * K + ks] = (_Float16)r;
      return;
    }
    idx -= sz;
  }
}

// ---------------------------------------------------------------- K4: fill
__global__ void fill_kernel(CsrParams p) {
  int l = blockIdx.y;
  int k = blockIdx.x * 256 + threadIdx.x;
  if (k < p.nnz[l]) {
    int r = p.row[l][k];
    int pos = atomicAdd(&p.cnt[l][r], 1);
    p.colsout[l][pos] = p.col[l][k];
    p.valsout[l][pos] = p.val[l][k];
  }
}

// ---------------------------------------------------------------- pool (CSR gather, batch-affine, 8ch/thread)
__global__ __launch_bounds__(256) void pool_kernel(
    const float* __restrict__ x,
    const int* __restrict__ rowptr,
    const int* __restrict__ cols,
    const float* __restrict__ vals,
    float* __restrict__ out,
    int Vout, int Vin, int Cin) {
  const int lpr    = Cin >> 3;
  const int lshift = 31 - __clz(lpr);
  const int rpb    = 256 >> lshift;
  const int lr = threadIdx.x >> lshift;
  const int lc = threadIdx.x & (lpr - 1);
  const int b  = blockIdx.x & 7;            // XCD-affine batch
  const int n  = (blockIdx.x >> 3) * rpb + lr;
  const int c8 = lc << 3;
  const float* xb = x + (size_t)b * Vin * Cin + c8;
  int j0 = rowptr[n], j1 = rowptr[n + 1];
  int cnt = j1 - j0;
  float4 a0 = make_float4(0.f, 0.f, 0.f, 0.f);
  float4 a1 = make_float4(0.f, 0.f, 0.f, 0.f);
  if (cnt > 0) {
    int   cc[4];
    float vv[4];
    #pragma unroll
    for (int k = 0; k < 4; ++k) {
      int jj = j0 + ((k < cnt) ? k : 0);    // in-bounds (cnt>0)
      cc[k] = cols[jj];
      vv[k] = (k < cnt) ? vals[jj] : 0.f;
    }
    #pragma unroll
    for (int k = 0; k < 4; ++k) {
      const float* xr = xb + (size_t)cc[k] * Cin;
      float4 x0 = *(const float4*)xr;
      float4 x1 = *(const float4*)(xr + 4);
      float v = vv[k];
      a0.x = fmaf(v, x0.x, a0.x); a0.y = fmaf(v, x0.y, a0.y);
      a0.z = fmaf(v, x0.z, a0.z); a0.w = fmaf(v, x0.w, a0.w);
      a1.x = fmaf(v, x1.x, a1.x); a1.y = fmaf(v, x1.y, a1.y);
      a1.z = fmaf(v, x1.z, a1.z); a1.w = fmaf(v, x1.w, a1.w);
    }
    for (int j = j0 + 4; j < j1; ++j) {     // rare tail (cnt>4)
      float v = vals[j];
      const float* xr = xb + (size_t)cols[j] * Cin;
      float4 x0 = *(const float4*)xr;
      float4 x1 = *(const float4*)(xr + 4);
      a0.x = fmaf(v, x0.x, a0.x); a0.y = fmaf(v, x0.y, a0.y);
      a0.z = fmaf(v, x0.z, a0.z); a0.w = fmaf(v, x0.w, a0.w);
      a1.x = fmaf(v, x1.x, a1.x); a1.y = fmaf(v, x1.y, a1.y);
      a1.z = fmaf(v, x1.z, a1.z); a1.w = fmaf(v, x1.w, a1.w);
    }
  }
  float* op = &out[((size_t)b * Vout + n) * Cin + c8];
  *(float4*)op = a0;
  *(float4*)(op + 4) = a1;
}

// ---------------------------------------------------------------- dw gather + f16x2 split (batch-affine, 8ch/thread)
// Output A planes PRE-SWIZZLED: chunk c of row m lands at c^(m&7).
__global__ __launch_bounds__(256) void dw_split_kernel(
    const float* __restrict__ xin,
    const int* __restrict__ sidx,
    const float* __restrict__ wd,
    _Float16* __restrict__ a0o,
    _Float16* __restrict__ a1o,
    int Vout, int Cin) {
  const int lpr    = Cin >> 3;
  const int lshift = 31 - __clz(lpr);
  const int rpb    = 256 >> lshift;
  const int lr = threadIdx.x >> lshift;
  const int lc = threadIdx.x & (lpr - 1);
  const int b  = blockIdx.x & 7;
  const int n  = (blockIdx.x >> 3) * rpb + lr;
  const int c8 = lc << 3;
  const float* xb = xin + (size_t)b * Vout * Cin + c8;

  int idx[9];
  #pragma unroll
  for (int s = 0; s < 9; ++s) idx[s] = sidx[n * 9 + s];

  float4 a0 = make_float4(0.f, 0.f, 0.f, 0.f);
  float4 a1 = make_float4(0.f, 0.f, 0.f, 0.f);
  #pragma unroll
  for (int s = 0; s < 9; ++s) {
    const float* xr = xb + (size_t)idx[s] * Cin;
    float4 x0 = *(const float4*)xr;
    float4 x1 = *(const float4*)(xr + 4);
    const float* wr = wd + s * Cin + c8;
    float4 w0 = *(const float4*)wr;
    float4 w1 = *(const float4*)(wr + 4);
    a0.x = fmaf(w0.x, x0.x, a0.x); a0.y = fmaf(w0.y, x0.y, a0.y);
    a0.z = fmaf(w0.z, x0.z, a0.z); a0.w = fmaf(w0.w, x0.w, a0.w);
    a1.x = fmaf(w1.x, x1.x, a1.x); a1.y = fmaf(w1.y, x1.y, a1.y);
    a1.z = fmaf(w1.z, x1.z, a1.z); a1.w = fmaf(w1.w, x1.w, a1.w);
  }

  size_t m = (size_t)b * Vout + n;
  float v[8] = {a0.x, a0.y, a0.z, a0.w, a1.x, a1.y, a1.z, a1.w};
  f16x8 hi, lo;
  #pragma unroll
  for (int i = 0; i < 8; ++i) {
    _Float16 h0 = (_Float16)v[i];
    float r = (v[i] - (float)h0) * 2048.0f;   // exact pow2; lo-plane stays normal
    hi[i] = h0;
    lo[i] = (_Float16)r;
  }
  const int c8s = (lc ^ (n & 7)) << 3;        // swizzled chunk position
  *(f16x8*)&a0o[m * Cin + c8s] = hi;
  *(f16x8*)&a1o[m * Cin + c8s] = lo;
}

// ---------------------------------------------------------------- f16x2-split MFMA GEMM + bias + relu (batch-affine)
// BM=128, BN=64, BK=64; 2x2 waves, wave tile 64x32, mfma 16x16x32.
// Staging via global_load_lds (16B/lane, linear LDS); operands pre-swizzled
// in global (chunk^(row&7)), reads apply the same XOR. LDS 48KB.
__global__ __launch_bounds__(256) void gemm_f16x2(
    const _Float16* __restrict__ A0, const _Float16* __restrict__ A1,
    const _Float16* __restrict__ Bt0, const _Float16* __restrict__ Bt1,
    const float* __restrict__ bias, float* __restrict__ C,
    int M, int N, int K) {
  __shared__ _Float16 As[2][128 * 64];      // linear; halves index = chunk*8
  __shared__ _Float16 Bs[2][64 * 64];
  const int tid = threadIdx.x;
  const int bx = blockIdx.x;
  const int xr_ = (bx & 7) * (gridDim.x >> 3) + (bx >> 3);   // batch-affine remap
  const int m0 = xr_ * 128, n0 = blockIdx.y * 64;
  const int wid = tid >> 6, lane = tid & 63;
  const int wr = wid >> 1, wc = wid & 1;
  const int lo = lane & 15, hi = lane >> 4;

  f32x4 accM[4][2], accC[4][2];
  #pragma unroll
  for (int mi = 0; mi < 4; ++mi)
    #pragma unroll
    for (int nj = 0; nj < 2; ++nj) {
      accM[mi][nj] = (f32x4){0.f, 0.f, 0.f, 0.f};
      accC[mi][nj] = (f32x4){0.f, 0.f, 0.f, 0.f};
    }

  const _Float16* gA[2] = {A0, A1};
  const _Float16* gB[2] = {Bt0, Bt1};

  for (int k0 = 0; k0 < K; k0 += 64) {
    #pragma unroll
    for (int p = 0; p < 2; ++p) {
      #pragma unroll
      for (int i = 0; i < 4; ++i) {          // A plane: 1024 16B chunks
        int c = tid + 256 * i;
        int r = c >> 3, k8 = (c & 7) << 3;
        gload_lds16(gA[p] + (size_t)(m0 + r) * K + k0 + k8,
                    &As[p][(c & ~63) * 8]);  // wave-uniform base; HW adds lane*16B
      }
      #pragma unroll
      for (int i = 0; i < 2; ++i) {          // B plane: 512 chunks
        int c = tid + 256 * i;
        int r = c >> 3, k8 = (c & 7) << 3;
        gload_lds16(gB[p] + (size_t)(n0 + r) * K + k0 + k8,
                    &Bs[p][(c & ~63) * 8]);
      }
    }
    __syncthreads();                          // compiler drains vmcnt before barrier
    #pragma unroll
    for (int s = 0; s < 2; ++s) {
      const int cl = s * 4 + hi;              // local chunk 0..7 (kk = cl*8)
      f16x8 af[4][2], bf[2][2];
      #pragma unroll
      for (int mi = 0; mi < 4; ++mi) {
        const int rr = wr * 64 + mi * 16 + lo;
        const int ko = (cl ^ (rr & 7)) << 3;  // un-swizzle on read
        af[mi][0] = *(const f16x8*)&As[0][rr * 64 + ko];
        af[mi][1] = *(const f16x8*)&As[1][rr * 64 + ko];
      }
      #pragma unroll
      for (int nj = 0; nj < 2; ++nj) {
        const int rb = wc * 32 + nj * 16 + lo;
        const int ko = (cl ^ (rb & 7)) << 3;
        bf[nj][0] = *(const f16x8*)&Bs[0][rb * 64 + ko];
        bf[nj][1] = *(const f16x8*)&Bs[1][rb * 64 + ko];
      }
      #pragma unroll
      for (int mi = 0; mi < 4; ++mi)
        #pragma unroll
        for (int nj = 0; nj < 2; ++nj) {
          accM[mi][nj] = __builtin_amdgcn_mfma_f32_16x16x32_f16(
              af[mi][0], bf[nj][0], accM[mi][nj], 0, 0, 0);
          accC[mi][nj] = __builtin_amdgcn_mfma_f32_16x16x32_f16(
              af[mi][0], bf[nj][1], accC[mi][nj], 0, 0, 0);
          accC[mi][nj] = __builtin_amdgcn_mfma_f32_16x16x32_f16(
              af[mi][1], bf[nj][0], accC[mi][nj], 0, 0, 0);
        }
    }
    __syncthreads();
  }

  const float INV = 1.0f / 2048.0f;
  #pragma unroll
  for (int mi = 0; mi < 4; ++mi)
    #pragma unroll
    for (int nj = 0; nj < 2; ++nj) {
      int col = n0 + wc * 32 + nj * 16 + lo;
      float bv = bias[col];
      #pragma unroll
      for (int r = 0; r < 4; ++r) {
        int row = m0 + wr * 64 + mi * 16 + hi * 4 + r;
        float v = accM[mi][nj][r] + accC[mi][nj][r] * INV + bv;
        v = fmaxf(v, 0.f);
        C[(size_t)row * N + col] = v;
      }
    }
}

// ---------------------------------------------------------------- fused head: dw (Cin=64, lane=channel) + 64x3 proj
__global__ __launch_bounds__(256) void head_fused_kernel(
    const float* __restrict__ x,      // [8][8192][64]
    const int* __restrict__ sidx,     // [8192][9]
    const float* __restrict__ wdh,    // [9][64]
    const float* __restrict__ wph,    // [64][3]
    const float* __restrict__ bh,
    float* __restrict__ out) {        // [8][8192][3]
  const int bid  = blockIdx.x;
  const int b    = bid & 7;           // XCD-affine batch
  const int wid  = threadIdx.x >> 6;
  const int lane = threadIdx.x & 63;
  const int n    = (bid >> 3) * 4 + wid;
  const float* xb = x + (size_t)b * 8192 * 64 + lane;

  int idx[9];
  #pragma unroll
  for (int s = 0; s < 9; ++s) idx[s] = sidx[n * 9 + s];

  float acc = 0.f;
  #pragma unroll
  for (int s = 0; s < 9; ++s)
    acc = fmaf(wdh[s * 64 + lane], xb[(size_t)idx[s] * 64], acc);

  float a0 = acc * wph[lane * 3 + 0];
  float a1 = acc * wph[lane * 3 + 1];
  float a2 = acc * wph[lane * 3 + 2];
  for (int off = 32; off > 0; off >>= 1) {
    a0 += __shfl_down(a0, off);
    a1 += __shfl_down(a1, off);
    a2 += __shfl_down(a2, off);
  }
  if (lane == 0) {
    size_t row = (size_t)b * 8192 + n;
    out[row * 3 + 0] = a0 + bh[0];
    out[row * 3 + 1] = a1 + bh[1];
    out[row * 3 + 2] = a2 + bh[2];
  }
}

// ---------------------------------------------------------------- launch
extern "C" void kernel_launch(void* const* d_in, const int* in_sizes, int n_in,
                              void* d_out, int out_size, void* d_ws, size_t ws_size,
                              hipStream_t stream) {
  const float* uv   = (const float*)d_in[0];
  const float* feat = (const float*)d_in[1];
  const float* up   = (const float*)d_in[2];
  const int* sArr[4] = {(const int*)d_in[3], (const int*)d_in[4],
                        (const int*)d_in[5], (const int*)d_in[6]};

  // workspace layout
  const size_t SLAB = 8ull * 2048 * 512;            // 8,388,608 elements
  float* Wf = (float*)d_ws;
  float* S0 = Wf;                                   // fp32 slab (x / gemm out); live < 4.2M floats
  float* S1 = Wf + SLAB;                            // fp32 slab (pool out)
  _Float16* A0 = (_Float16*)(S1 + SLAB);            // dw hi plane (pre-swizzled)
  _Float16* A1 = A0 + SLAB;                         // dw lo plane
  _Float16* Bt0all = (_Float16*)(S0 + 4500000);     // dead upper part of S0
  _Float16* Bt1all = Bt0all + 434176;
  float* xs = (float*)(A1 + SLAB);                  // B*P*512 floats
  int* ib = (int*)(xs + (size_t)B_ * P_ * 512);

  int Vt[4] = {1024, 2048, 4096, 8192};
  int NZ[4] = {3072, 6144, 12288, 24576};
  int* cnt[4]; int* rp[4]; int* co[4]; float* va[4];
  {
    int* pc = ib;
    for (int t = 0; t < 4; ++t) { cnt[t] = pc; pc += Vt[t]; }          // 15360 ints
    for (int t = 0; t < 4; ++t) { rp[t] = pc; pc += Vt[t] + 1; }
    for (int t = 0; t < 4; ++t) { co[t] = pc; pc += NZ[t]; }
    float* pv = (float*)pc;
    for (int t = 0; t < 4; ++t) { va[t] = pv; pv += NZ[t]; }
  }

  CsrParams cp;
  for (int t = 0; t < 4; ++t) {
    int i = 3 - t;
    cp.row[t] = (const int*)d_in[7 + 3 * i];
    cp.col[t] = (const int*)d_in[8 + 3 * i];
    cp.val[t] = (const float*)d_in[9 + 3 * i];
    cp.cnt[t] = cnt[t]; cp.rowptr[t] = rp[t];
    cp.colsout[t] = co[t]; cp.valsout[t] = va[t];
    cp.nnz[t] = NZ[t]; cp.V[t] = Vt[t];
  }

  struct Stg { int Vin, Vout, Cin, Cout; const int* s; const float *wd, *wp, *bias; };
  Stg st[4] = {
    {512, 1024, 512, 512, sArr[3], (const float*)d_in[19], (const float*)d_in[20], (const float*)d_in[21]},
    {1024, 2048, 512, 256, sArr[2], (const float*)d_in[22], (const float*)d_in[23], (const float*)d_in[24]},
    {2048, 4096, 256, 128, sArr[1], (const float*)d_in[25], (const float*)d_in[26], (const float*)d_in[27]},
    {4096, 8192, 128, 64, sArr[0], (const float*)d_in[28], (const float*)d_in[29], (const float*)d_in[30]},
  };

  BsplitParams bp;
  int boff = 0;
  for (int t = 0; t < 4; ++t) {
    bp.wp[t] = st[t].wp;
    bp.K[t] = st[t].Cin; bp.N[t] = st[t].Cout;
    bp.off[t] = boff;
    boff += st[t].Cin * st[t].Cout;           // 434176 total
  }
  bp.b0 = Bt0all; bp.b1 = Bt1all;
  int bsplit_blocks = (boff + 255) / 256;     // 1696

  // front matter: 4 merged kernels (3 independent chains interleaved)
  k1_zero_sample<<<60 + B_ * P_, 256, 0, stream>>>(ib, 15360, uv, feat, xs);
  k2_count_upsample<<<384 + 512 * B_, 256, 0, stream>>>(cp, up, xs, S0);
  k3_scan_bsplit<<<4 + bsplit_blocks, 256, 0, stream>>>(cp, bp);
  fill_kernel<<<dim3(96, 4), 256, 0, stream>>>(cp);

  for (int t = 0; t < 4; ++t) {
    int rpb = 2048 / st[t].Cin;               // rows/block at 8 ch/thread
    pool_kernel<<<8 * (st[t].Vout / rpb), 256, 0, stream>>>(
        S0, rp[t], co[t], va[t], S1, st[t].Vout, st[t].Vin, st[t].Cin);
    dw_split_kernel<<<8 * (st[t].Vout / rpb), 256, 0, stream>>>(
        S1, st[t].s, st[t].wd, A0, A1, st[t].Vout, st[t].Cin);
    int M = B_ * st[t].Vout;
    gemm_f16x2<<<dim3(M / 128, st[t].Cout / 64), 256, 0, stream>>>(
        A0, A1, Bt0all + bp.off[t], Bt1all + bp.off[t],
        st[t].bias, S0, M, st[t].Cout, st[t].Cin);
  }

  // fused head: dw (K=64) + 64x3 projection, one launch
  head_fused_kernel<<<8 * (8192 / 4), 256, 0, stream>>>(
      S0, sArr[0], (const float*)d_in[31], (const float*)d_in[32],
      (const float*)d_in[33], (float*)d_out);
}

// Round 18
// 264.279 us; speedup vs baseline: 2.0107x; 1.0058x over previous
//
#include <hip/hip_runtime.h>

#define B_  8
#define P_  21
#define H_  32
#define W_  32

typedef float f32x4 __attribute__((ext_vector_type(4)));
typedef _Float16 f16x8 __attribute__((ext_vector_type(8)));

// async global->LDS, 16B per lane; LDS dst must be wave-uniform base (HW adds lane*16)
__device__ __forceinline__ void gload_lds16(const _Float16* g, _Float16* l) {
  __builtin_amdgcn_global_load_lds(
      (const __attribute__((address_space(1))) void*)g,
      (__attribute__((address_space(3))) void*)l, 16, 0, 0);
}

// ---------------------------------------------------------------- CSR build structs
struct CsrParams {
  const int*   row[4];
  const int*   col[4];
  const float* val[4];
  int*   cnt[4];
  int*   rowptr[4];
  int*   colsout[4];
  float* valsout[4];
  int    nnz[4];
  int    V[4];
};

struct BsplitParams {
  const float* wp[4];
  int K[4], N[4], off[4];
  _Float16* b0;
  _Float16* b1;
};

// ---------------------------------------------------------------- K1: zero (60 blks) || sample (168 blks)
__global__ __launch_bounds__(256) void k1_zero_sample(
    int* zp, int zn,
    const float* __restrict__ uv,
    const float* __restrict__ feat,
    float* __restrict__ xs) {
  int bid = blockIdx.x;
  if (bid < 60) {
    int i = bid * 256 + threadIdx.x;
    if (i < zn) zp[i] = 0;
    return;
  }
  int bp = bid - 60;                 // b*21+p
  int b  = bp / P_;
  float u0 = uv[bp * 2 + 0], u1 = uv[bp * 2 + 1];
  float gx = fminf(fmaxf((u0 - 0.5f) * 2.0f, -1.0f), 1.0f);
  float gy = fminf(fmaxf((u1 - 0.5f) * 2.0f, -1.0f), 1.0f);
  float fx = (gx + 1.0f) * 0.5f * (W_ - 1);
  float fy = (gy + 1.0f) * 0.5f * (H_ - 1);
  float x0f = floorf(fx), y0f = floorf(fy);
  float wx = fx - x0f, wy = fy - y0f;
  int x0 = (int)x0f, y0 = (int)y0f;
  int x0i = min(max(x0, 0), W_ - 1), x1i = min(max(x0 + 1, 0), W_ - 1);
  int y0i = min(max(y0, 0), H_ - 1), y1i = min(max(y0 + 1, 0), H_ - 1);
  float w00 = (1.f - wy) * (1.f - wx), w01 = (1.f - wy) * wx;
  float w10 = wy * (1.f - wx),        w11 = wy * wx;
  for (int c = threadIdx.x; c < 512; c += blockDim.x) {
    const float* fb = feat + ((size_t)(b * 512 + c)) * (H_ * W_);
    float v = fb[y0i * W_ + x0i] * w00 + fb[y0i * W_ + x1i] * w01 +
              fb[y1i * W_ + x0i] * w10 + fb[y1i * W_ + x1i] * w11;
    xs[(size_t)bp * 512 + c] = v;
  }
}

// ---------------------------------------------------------------- K2: count (384 blks) || upsample (4096 blks)
__global__ __launch_bounds__(256) void k2_count_upsample(
    CsrParams p,
    const float* __restrict__ up,
    const float* __restrict__ xs,
    float* __restrict__ xu) {
  int bid = blockIdx.x;
  if (bid < 384) {
    int l = bid / 96;
    int k = (bid - l * 96) * 256 + threadIdx.x;
    if (k < p.nnz[l]) atomicAdd(&p.cnt[l][p.row[l][k]], 1);
    return;
  }
  int b2 = bid - 384;                // [0, 4096)
  int b = b2 >> 9, v = b2 & 511;
  int c2 = threadIdx.x << 1;         // 256 thr * 2 ch = 512
  float2 acc = make_float2(0.f, 0.f);
  for (int q = 0; q < P_; ++q) {
    float u = up[v * P_ + q];
    const float2 xv = *(const float2*)&xs[((size_t)(b * P_ + q)) * 512 + c2];
    acc.x = fmaf(u, xv.x, acc.x);
    acc.y = fmaf(u, xv.y, acc.y);
  }
  *(float2*)&xu[((size_t)(b * 512 + v)) * 512 + c2] = acc;
}

// ---------------------------------------------------------------- K3: scan (4 blks) || bsplit (rest)
__global__ __launch_bounds__(256) void k3_scan_bsplit(CsrParams p, BsplitParams bp) {
  int bid = blockIdx.x;
  if (bid < 4) {
    int l = bid;
    int V = p.V[l];
    int* cnt = p.cnt[l];
    int* rp  = p.rowptr[l];
    int t = threadIdx.x;
    int chunk = V / 256;
    int base = t * chunk;
    int s = 0;
    for (int i = 0; i < chunk; ++i) s += cnt[base + i];
    __shared__ int sm[256];
    sm[t] = s;
    __syncthreads();
    for (int off = 1; off < 256; off <<= 1) {
      int v = (t >= off) ? sm[t - off] : 0;
      __syncthreads();
      sm[t] += v;
      __syncthreads();
    }
    int run = sm[t] - s;
    for (int i = 0; i < chunk; ++i) {
      int c = cnt[base + i];
      rp[base + i]  = run;
      cnt[base + i] = run;
      run += c;
    }
    if (t == 255) rp[V] = run;
    return;
  }
  int idx = (bid - 4) * 256 + threadIdx.x;
  #pragma unroll
  for (int t = 0; t < 4; ++t) {
    int sz = bp.N[t] * bp.K[t];
    if (idx < sz) {
      int K = bp.K[t];
      int n = idx / K, k = idx - n * K;
      float v = bp.wp[t][(size_t)k * bp.N[t] + n];
      _Float16 h0 = (_Float16)v;
      float r = (v - (float)h0) * 2048.0f;
      int ks = ((((k >> 3) ^ (n & 7)) << 3) | (k & 7));   // chunk-XOR swizzle
      bp.b0[bp.off[t] + (size_t)n * K + ks] = h0;
      bp.b1[bp.off[t] + (size_t)n * K + ks] = (_Float16)r;
      return;
    }
    idx -= sz;
  }
}

// ---------------------------------------------------------------- K4: fill
__global__ void fill_kernel(CsrParams p) {
  int l = blockIdx.y;
  int k = blockIdx.x * 256 + threadIdx.x;
  if (k < p.nnz[l]) {
    int r = p.row[l][k];
    int pos = atomicAdd(&p.cnt[l][r], 1);
    p.colsout[l][pos] = p.col[l][k];
    p.valsout[l][pos] = p.val[l][k];
  }
}

// ---------------------------------------------------------------- pool (CSR gather, batch-affine, 8ch/thread)
// For Cin>=512 one row spans a full wave -> rowptr/cols/vals are wave-uniform;
// readfirstlane makes them SGPR (s_load), freeing VMEM slots on the gather path.
__global__ __launch_bounds__(256) void pool_kernel(
    const float* __restrict__ x,
    const int* __restrict__ rowptr,
    const int* __restrict__ cols,
    const float* __restrict__ vals,
    float* __restrict__ out,
    int Vout, int Vin, int Cin) {
  const int lpr    = Cin >> 3;
  const int lshift = 31 - __clz(lpr);
  const int rpb    = 256 >> lshift;
  const int lr = threadIdx.x >> lshift;
  const int lc = threadIdx.x & (lpr - 1);
  const int b  = blockIdx.x & 7;            // XCD-affine batch
  const int n  = (blockIdx.x >> 3) * rpb + lr;
  const int c8 = lc << 3;
  const float* xb = x + (size_t)b * Vin * Cin + c8;
  const int nu = (lpr >= 64) ? __builtin_amdgcn_readfirstlane(n) : n;
  int j0 = rowptr[nu], j1 = rowptr[nu + 1];
  int cnt = j1 - j0;
  float4 a0 = make_float4(0.f, 0.f, 0.f, 0.f);
  float4 a1 = make_float4(0.f, 0.f, 0.f, 0.f);
  if (cnt > 0) {
    int   cc[4];
    float vv[4];
    #pragma unroll
    for (int k = 0; k < 4; ++k) {
      int jj = j0 + ((k < cnt) ? k : 0);    // in-bounds (cnt>0)
      cc[k] = cols[jj];
      vv[k] = (k < cnt) ? vals[jj] : 0.f;
    }
    #pragma unroll
    for (int k = 0; k < 4; ++k) {
      const float* xr = xb + (size_t)cc[k] * Cin;
      float4 x0 = *(const float4*)xr;
      float4 x1 = *(const float4*)(xr + 4);
      float v = vv[k];
      a0.x = fmaf(v, x0.x, a0.x); a0.y = fmaf(v, x0.y, a0.y);
      a0.z = fmaf(v, x0.z, a0.z); a0.w = fmaf(v, x0.w, a0.w);
      a1.x = fmaf(v, x1.x, a1.x); a1.y = fmaf(v, x1.y, a1.y);
      a1.z = fmaf(v, x1.z, a1.z); a1.w = fmaf(v, x1.w, a1.w);
    }
    for (int j = j0 + 4; j < j1; ++j) {     // rare tail (cnt>4)
      float v = vals[j];
      const float* xr = xb + (size_t)cols[j] * Cin;
      float4 x0 = *(const float4*)xr;
      float4 x1 = *(const float4*)(xr + 4);
      a0.x = fmaf(v, x0.x, a0.x); a0.y = fmaf(v, x0.y, a0.y);
      a0.z = fmaf(v, x0.z, a0.z); a0.w = fmaf(v, x0.w, a0.w);
      a1.x = fmaf(v, x1.x, a1.x); a1.y = fmaf(v, x1.y, a1.y);
      a1.z = fmaf(v, x1.z, a1.z); a1.w = fmaf(v, x1.w, a1.w);
    }
  }
  float* op = &out[((size_t)b * Vout + n) * Cin + c8];
  *(float4*)op = a0;
  *(float4*)(op + 4) = a1;
}

// ---------------------------------------------------------------- dw gather + f16x2 split (batch-affine, 8ch/thread)
// Output A planes PRE-SWIZZLED: chunk c of row m lands at c^(m&7).
// Wave-uniform sidx reads scalarized for Cin>=512.
__global__ __launch_bounds__(256) void dw_split_kernel(
    const float* __restrict__ xin,
    const int* __restrict__ sidx,
    const float* __restrict__ wd,
    _Float16* __restrict__ a0o,
    _Float16* __restrict__ a1o,
    int Vout, int Cin) {
  const int lpr    = Cin >> 3;
  const int lshift = 31 - __clz(lpr);
  const int rpb    = 256 >> lshift;
  const int lr = threadIdx.x >> lshift;
  const int lc = threadIdx.x & (lpr - 1);
  const int b  = blockIdx.x & 7;
  const int n  = (blockIdx.x >> 3) * rpb + lr;
  const int c8 = lc << 3;
  const float* xb = xin + (size_t)b * Vout * Cin + c8;
  const int nu = (lpr >= 64) ? __builtin_amdgcn_readfirstlane(n) : n;

  int idx[9];
  #pragma unroll
  for (int s = 0; s < 9; ++s) idx[s] = sidx[nu * 9 + s];

  float4 a0 = make_float4(0.f, 0.f, 0.f, 0.f);
  float4 a1 = make_float4(0.f, 0.f, 0.f, 0.f);
  #pragma unroll
  for (int s = 0; s < 9; ++s) {
    const float* xr = xb + (size_t)idx[s] * Cin;
    float4 x0 = *(const float4*)xr;
    float4 x1 = *(const float4*)(xr + 4);
    const float* wr = wd + s * Cin + c8;
    float4 w0 = *(const float4*)wr;
    float4 w1 = *(const float4*)(wr + 4);
    a0.x = fmaf(w0.x, x0.x, a0.x); a0.y = fmaf(w0.y, x0.y, a0.y);
    a0.z = fmaf(w0.z, x0.z, a0.z); a0.w = fmaf(w0.w, x0.w, a0.w);
    a1.x = fmaf(w1.x, x1.x, a1.x); a1.y = fmaf(w1.y, x1.y, a1.y);
    a1.z = fmaf(w1.z, x1.z, a1.z); a1.w = fmaf(w1.w, x1.w, a1.w);
  }

  size_t m = (size_t)b * Vout + n;
  float v[8] = {a0.x, a0.y, a0.z, a0.w, a1.x, a1.y, a1.z, a1.w};
  f16x8 hi, lo;
  #pragma unroll
  for (int i = 0; i < 8; ++i) {
    _Float16 h0 = (_Float16)v[i];
    float r = (v[i] - (float)h0) * 2048.0f;   // exact pow2; lo-plane stays normal
    hi[i] = h0;
    lo[i] = (_Float16)r;
  }
  const int c8s = (lc ^ (n & 7)) << 3;        // swizzled chunk position
  *(f16x8*)&a0o[m * Cin + c8s] = hi;
  *(f16x8*)&a1o[m * Cin + c8s] = lo;
}

// ---------------------------------------------------------------- f16x2-split MFMA GEMM + bias + relu (batch-affine)
// BM=128, BN=64, BK=64; 2x2 waves, wave tile 64x32, mfma 16x16x32.
// Staging via global_load_lds (16B/lane, linear LDS); operands pre-swizzled
// in global (chunk^(row&7)), reads apply the same XOR. LDS 48KB.
__global__ __launch_bounds__(256) void gemm_f16x2(
    const _Float16* __restrict__ A0, const _Float16* __restrict__ A1,
    const _Float16* __restrict__ Bt0, const _Float16* __restrict__ Bt1,
    const float* __restrict__ bias, float* __restrict__ C,
    int M, int N, int K) {
  __shared__ _Float16 As[2][128 * 64];      // linear; halves index = chunk*8
  __shared__ _Float16 Bs[2][64 * 64];
  const int tid = threadIdx.x;
  const int bx = blockIdx.x;
  const int xr_ = (bx & 7) * (gridDim.x >> 3) + (bx >> 3);   // batch-affine remap
  const int m0 = xr_ * 128, n0 = blockIdx.y * 64;
  const int wid = tid >> 6, lane = tid & 63;
  const int wr = wid >> 1, wc = wid & 1;
  const int lo = lane & 15, hi = lane >> 4;

  // hoist bias loads: latency hides under the K-loop instead of the epilogue
  float bv[2];
  bv[0] = bias[n0 + wc * 32 + 0 * 16 + lo];
  bv[1] = bias[n0 + wc * 32 + 1 * 16 + lo];

  f32x4 accM[4][2], accC[4][2];
  #pragma unroll
  for (int mi = 0; mi < 4; ++mi)
    #pragma unroll
    for (int nj = 0; nj < 2; ++nj) {
      accM[mi][nj] = (f32x4){0.f, 0.f, 0.f, 0.f};
      accC[mi][nj] = (f32x4){0.f, 0.f, 0.f, 0.f};
    }

  const _Float16* gA[2] = {A0, A1};
  const _Float16* gB[2] = {Bt0, Bt1};

  for (int k0 = 0; k0 < K; k0 += 64) {
    #pragma unroll
    for (int p = 0; p < 2; ++p) {
      #pragma unroll
      for (int i = 0; i < 4; ++i) {          // A plane: 1024 16B chunks
        int c = tid + 256 * i;
        int r = c >> 3, k8 = (c & 7) << 3;
        gload_lds16(gA[p] + (size_t)(m0 + r) * K + k0 + k8,
                    &As[p][(c & ~63) * 8]);  // wave-uniform base; HW adds lane*16B
      }
      #pragma unroll
      for (int i = 0; i < 2; ++i) {          // B plane: 512 chunks
        int c = tid + 256 * i;
        int r = c >> 3, k8 = (c & 7) << 3;
        gload_lds16(gB[p] + (size_t)(n0 + r) * K + k0 + k8,
                    &Bs[p][(c & ~63) * 8]);
      }
    }
    __syncthreads();                          // compiler drains vmcnt before barrier
    #pragma unroll
    for (int s = 0; s < 2; ++s) {
      const int cl = s * 4 + hi;              // local chunk 0..7 (kk = cl*8)
      f16x8 af[4][2], bf[2][2];
      #pragma unroll
      for (int mi = 0; mi < 4; ++mi) {
        const int rr = wr * 64 + mi * 16 + lo;
        const int ko = (cl ^ (rr & 7)) << 3;  // un-swizzle on read
        af[mi][0] = *(const f16x8*)&As[0][rr * 64 + ko];
        af[mi][1] = *(const f16x8*)&As[1][rr * 64 + ko];
      }
      #pragma unroll
      for (int nj = 0; nj < 2; ++nj) {
        const int rb = wc * 32 + nj * 16 + lo;
        const int ko = (cl ^ (rb & 7)) << 3;
        bf[nj][0] = *(const f16x8*)&Bs[0][rb * 64 + ko];
        bf[nj][1] = *(const f16x8*)&Bs[1][rb * 64 + ko];
      }
      #pragma unroll
      for (int mi = 0; mi < 4; ++mi)
        #pragma unroll
        for (int nj = 0; nj < 2; ++nj) {
          accM[mi][nj] = __builtin_amdgcn_mfma_f32_16x16x32_f16(
              af[mi][0], bf[nj][0], accM[mi][nj], 0, 0, 0);
          accC[mi][nj] = __builtin_amdgcn_mfma_f32_16x16x32_f16(
              af[mi][0], bf[nj][1], accC[mi][nj], 0, 0, 0);
          accC[mi][nj] = __builtin_amdgcn_mfma_f32_16x16x32_f16(
              af[mi][1], bf[nj][0], accC[mi][nj], 0, 0, 0);
        }
    }
    __syncthreads();
  }

  const float INV = 1.0f / 2048.0f;
  #pragma unroll
  for (int mi = 0; mi < 4; ++mi)
    #pragma unroll
    for (int nj = 0; nj < 2; ++nj) {
      int col = n0 + wc * 32 + nj * 16 + lo;
      #pragma unroll
      for (int r = 0; r < 4; ++r) {
        int row = m0 + wr * 64 + mi * 16 + hi * 4 + r;
        float v = accM[mi][nj][r] + accC[mi][nj][r] * INV + bv[nj];
        v = fmaxf(v, 0.f);
        C[(size_t)row * N + col] = v;
      }
    }
}

// ---------------------------------------------------------------- fused head: dw (Cin=64, lane=channel) + 64x3 proj
// 2 rows per wave: 18 gathers in flight, half the waves.
__global__ __launch_bounds__(256) void head_fused_kernel(
    const float* __restrict__ x,      // [8][8192][64]
    const int* __restrict__ sidx,     // [8192][9]
    const float* __restrict__ wdh,    // [9][64]
    const float* __restrict__ wph,    // [64][3]
    const float* __restrict__ bh,
    float* __restrict__ out) {        // [8][8192][3]
  const int bid  = blockIdx.x;
  const int b    = bid & 7;           // XCD-affine batch
  const int wid  = threadIdx.x >> 6;
  const int lane = threadIdx.x & 63;
  const int n0   = (bid >> 3) * 8 + wid;   // rows n0 and n0+4
  const int n1   = n0 + 4;
  const float* xb = x + (size_t)b * 8192 * 64 + lane;

  int idx0[9], idx1[9];
  #pragma unroll
  for (int s = 0; s < 9; ++s) idx0[s] = sidx[n0 * 9 + s];
  #pragma unroll
  for (int s = 0; s < 9; ++s) idx1[s] = sidx[n1 * 9 + s];

  float acc0 = 0.f, acc1 = 0.f;
  #pragma unroll
  for (int s = 0; s < 9; ++s) {
    float w = wdh[s * 64 + lane];
    acc0 = fmaf(w, xb[(size_t)idx0[s] * 64], acc0);
    acc1 = fmaf(w, xb[(size_t)idx1[s] * 64], acc1);
  }

  float p0 = wph[lane * 3 + 0];
  float p1 = wph[lane * 3 + 1];
  float p2 = wph[lane * 3 + 2];
  float a00 = acc0 * p0, a01 = acc0 * p1, a02 = acc0 * p2;
  float a10 = acc1 * p0, a11 = acc1 * p1, a12 = acc1 * p2;
  for (int off = 32; off > 0; off >>= 1) {
    a00 += __shfl_down(a00, off);
    a01 += __shfl_down(a01, off);
    a02 += __shfl_down(a02, off);
    a10 += __shfl_down(a10, off);
    a11 += __shfl_down(a11, off);
    a12 += __shfl_down(a12, off);
  }
  if (lane == 0) {
    size_t row0 = (size_t)b * 8192 + n0;
    out[row0 * 3 + 0] = a00 + bh[0];
    out[row0 * 3 + 1] = a01 + bh[1];
    out[row0 * 3 + 2] = a02 + bh[2];
    size_t row1 = (size_t)b * 8192 + n1;
    out[row1 * 3 + 0] = a10 + bh[0];
    out[row1 * 3 + 1] = a11 + bh[1];
    out[row1 * 3 + 2] = a12 + bh[2];
  }
}

// ---------------------------------------------------------------- launch
extern "C" void kernel_launch(void* const* d_in, const int* in_sizes, int n_in,
                              void* d_out, int out_size, void* d_ws, size_t ws_size,
                              hipStream_t stream) {
  const float* uv   = (const float*)d_in[0];
  const float* feat = (const float*)d_in[1];
  const float* up   = (const float*)d_in[2];
  const int* sArr[4] = {(const int*)d_in[3], (const int*)d_in[4],
                        (const int*)d_in[5], (const int*)d_in[6]};

  // workspace layout
  const size_t SLAB = 8ull * 2048 * 512;            // 8,388,608 elements
  float* Wf = (float*)d_ws;
  float* S0 = Wf;                                   // fp32 slab (x / gemm out); live < 4.2M floats
  float* S1 = Wf + SLAB;                            // fp32 slab (pool out)
  _Float16* A0 = (_Float16*)(S1 + SLAB);            // dw hi plane (pre-swizzled)
  _Float16* A1 = A0 + SLAB;                         // dw lo plane
  _Float16* Bt0all = (_Float16*)(S0 + 4500000);     // dead upper part of S0
  _Float16* Bt1all = Bt0all + 434176;
  float* xs = (float*)(A1 + SLAB);                  // B*P*512 floats
  int* ib = (int*)(xs + (size_t)B_ * P_ * 512);

  int Vt[4] = {1024, 2048, 4096, 8192};
  int NZ[4] = {3072, 6144, 12288, 24576};
  int* cnt[4]; int* rp[4]; int* co[4]; float* va[4];
  {
    int* pc = ib;
    for (int t = 0; t < 4; ++t) { cnt[t] = pc; pc += Vt[t]; }          // 15360 ints
    for (int t = 0; t < 4; ++t) { rp[t] = pc; pc += Vt[t] + 1; }
    for (int t = 0; t < 4; ++t) { co[t] = pc; pc += NZ[t]; }
    float* pv = (float*)pc;
    for (int t = 0; t < 4; ++t) { va[t] = pv; pv += NZ[t]; }
  }

  CsrParams cp;
  for (int t = 0; t < 4; ++t) {
    int i = 3 - t;
    cp.row[t] = (const int*)d_in[7 + 3 * i];
    cp.col[t] = (const int*)d_in[8 + 3 * i];
    cp.val[t] = (const float*)d_in[9 + 3 * i];
    cp.cnt[t] = cnt[t]; cp.rowptr[t] = rp[t];
    cp.colsout[t] = co[t]; cp.valsout[t] = va[t];
    cp.nnz[t] = NZ[t]; cp.V[t] = Vt[t];
  }

  struct Stg { int Vin, Vout, Cin, Cout; const int* s; const float *wd, *wp, *bias; };
  Stg st[4] = {
    {512, 1024, 512, 512, sArr[3], (const float*)d_in[19], (const float*)d_in[20], (const float*)d_in[21]},
    {1024, 2048, 512, 256, sArr[2], (const float*)d_in[22], (const float*)d_in[23], (const float*)d_in[24]},
    {2048, 4096, 256, 128, sArr[1], (const float*)d_in[25], (const float*)d_in[26], (const float*)d_in[27]},
    {4096, 8192, 128, 64, sArr[0], (const float*)d_in[28], (const float*)d_in[29], (const float*)d_in[30]},
  };

  BsplitParams bp;
  int boff = 0;
  for (int t = 0; t < 4; ++t) {
    bp.wp[t] = st[t].wp;
    bp.K[t] = st[t].Cin; bp.N[t] = st[t].Cout;
    bp.off[t] = boff;
    boff += st[t].Cin * st[t].Cout;           // 434176 total
  }
  bp.b0 = Bt0all; bp.b1 = Bt1all;
  int bsplit_blocks = (boff + 255) / 256;     // 1696

  // front matter: 4 merged kernels (3 independent chains interleaved)
  k1_zero_sample<<<60 + B_ * P_, 256, 0, stream>>>(ib, 15360, uv, feat, xs);
  k2_count_upsample<<<384 + 512 * B_, 256, 0, stream>>>(cp, up, xs, S0);
  k3_scan_bsplit<<<4 + bsplit_blocks, 256, 0, stream>>>(cp, bp);
  fill_kernel<<<dim3(96, 4), 256, 0, stream>>>(cp);

  for (int t = 0; t < 4; ++t) {
    int rpb = 2048 / st[t].Cin;               // rows/block at 8 ch/thread
    pool_kernel<<<8 * (st[t].Vout / rpb), 256, 0, stream>>>(
        S0, rp[t], co[t], va[t], S1, st[t].Vout, st[t].Vin, st[t].Cin);
    dw_split_kernel<<<8 * (st[t].Vout / rpb), 256, 0, stream>>>(
        S1, st[t].s, st[t].wd, A0, A1, st[t].Vout, st[t].Cin);
    int M = B_ * st[t].Vout;
    gemm_f16x2<<<dim3(M / 128, st[t].Cout / 64), 256, 0, stream>>>(
        A0, A1, Bt0all + bp.off[t], Bt1all + bp.off[t],
        st[t].bias, S0, M, st[t].Cout, st[t].Cin);
  }

  // fused head: dw (K=64) + 64x3 projection, 2 rows/wave
  head_fused_kernel<<<8 * (8192 / 8), 256, 0, stream>>>(
      S0, sArr[0], (const float*)d_in[31], (const float*)d_in[32],
      (const float*)d_in[33], (float*)d_out);
}

// Round 19
// 257.573 us; speedup vs baseline: 2.0631x; 1.0260x over previous
//
#include <hip/hip_runtime.h>

#define B_  8
#define P_  21
#define H_  32
#define W_  32

typedef float f32x4 __attribute__((ext_vector_type(4)));
typedef _Float16 f16x8 __attribute__((ext_vector_type(8)));

// async global->LDS, 16B per lane; LDS dst must be wave-uniform base (HW adds lane*16)
__device__ __forceinline__ void gload_lds16(const _Float16* g, _Float16* l) {
  __builtin_amdgcn_global_load_lds(
      (const __attribute__((address_space(1))) void*)g,
      (__attribute__((address_space(3))) void*)l, 16, 0, 0);
}

// ---------------------------------------------------------------- CSR build structs
struct CsrParams {
  const int*   row[4];
  const int*   col[4];
  const float* val[4];
  int*   cnt[4];
  int*   rowptr[4];
  int*   colsout[4];
  float* valsout[4];
  int    nnz[4];
  int    V[4];
};

struct BsplitParams {
  const float* wp[4];
  int K[4], N[4], off[4];
  _Float16* b0;
  _Float16* b1;
};

// ---------------------------------------------------------------- K1: zero (60 blks) || sample (168 blks)
__global__ __launch_bounds__(256) void k1_zero_sample(
    int* zp, int zn,
    const float* __restrict__ uv,
    const float* __restrict__ feat,
    float* __restrict__ xs) {
  int bid = blockIdx.x;
  if (bid < 60) {
    int i = bid * 256 + threadIdx.x;
    if (i < zn) zp[i] = 0;
    return;
  }
  int bp = bid - 60;                 // b*21+p
  int b  = bp / P_;
  float u0 = uv[bp * 2 + 0], u1 = uv[bp * 2 + 1];
  float gx = fminf(fmaxf((u0 - 0.5f) * 2.0f, -1.0f), 1.0f);
  float gy = fminf(fmaxf((u1 - 0.5f) * 2.0f, -1.0f), 1.0f);
  float fx = (gx + 1.0f) * 0.5f * (W_ - 1);
  float fy = (gy + 1.0f) * 0.5f * (H_ - 1);
  float x0f = floorf(fx), y0f = floorf(fy);
  float wx = fx - x0f, wy = fy - y0f;
  int x0 = (int)x0f, y0 = (int)y0f;
  int x0i = min(max(x0, 0), W_ - 1), x1i = min(max(x0 + 1, 0), W_ - 1);
  int y0i = min(max(y0, 0), H_ - 1), y1i = min(max(y0 + 1, 0), H_ - 1);
  float w00 = (1.f - wy) * (1.f - wx), w01 = (1.f - wy) * wx;
  float w10 = wy * (1.f - wx),        w11 = wy * wx;
  for (int c = threadIdx.x; c < 512; c += blockDim.x) {
    const float* fb = feat + ((size_t)(b * 512 + c)) * (H_ * W_);
    float v = fb[y0i * W_ + x0i] * w00 + fb[y0i * W_ + x1i] * w01 +
              fb[y1i * W_ + x0i] * w10 + fb[y1i * W_ + x1i] * w11;
    xs[(size_t)bp * 512 + c] = v;
  }
}

// ---------------------------------------------------------------- K2: count (384 blks) || upsample (4096 blks)
__global__ __launch_bounds__(256) void k2_count_upsample(
    CsrParams p,
    const float* __restrict__ up,
    const float* __restrict__ xs,
    float* __restrict__ xu) {
  int bid = blockIdx.x;
  if (bid < 384) {
    int l = bid / 96;
    int k = (bid - l * 96) * 256 + threadIdx.x;
    if (k < p.nnz[l]) atomicAdd(&p.cnt[l][p.row[l][k]], 1);
    return;
  }
  int b2 = bid - 384;                // [0, 4096)
  int b = b2 >> 9, v = b2 & 511;
  int c2 = threadIdx.x << 1;         // 256 thr * 2 ch = 512
  float2 acc = make_float2(0.f, 0.f);
  for (int q = 0; q < P_; ++q) {
    float u = up[v * P_ + q];
    const float2 xv = *(const float2*)&xs[((size_t)(b * P_ + q)) * 512 + c2];
    acc.x = fmaf(u, xv.x, acc.x);
    acc.y = fmaf(u, xv.y, acc.y);
  }
  *(float2*)&xu[((size_t)(b * 512 + v)) * 512 + c2] = acc;
}

// ---------------------------------------------------------------- K3: scan (4 blks) || bsplit (rest)
__global__ __launch_bounds__(256) void k3_scan_bsplit(CsrParams p, BsplitParams bp) {
  int bid = blockIdx.x;
  if (bid < 4) {
    int l = bid;
    int V = p.V[l];
    int* cnt = p.cnt[l];
    int* rp  = p.rowptr[l];
    int t = threadIdx.x;
    int chunk = V / 256;
    int base = t * chunk;
    int s = 0;
    for (int i = 0; i < chunk; ++i) s += cnt[base + i];
    __shared__ int sm[256];
    sm[t] = s;
    __syncthreads();
    for (int off = 1; off < 256; off <<= 1) {
      int v = (t >= off) ? sm[t - off] : 0;
      __syncthreads();
      sm[t] += v;
      __syncthreads();
    }
    int run = sm[t] - s;
    for (int i = 0; i < chunk; ++i) {
      int c = cnt[base + i];
      rp[base + i]  = run;
      cnt[base + i] = run;
      run += c;
    }
    if (t == 255) rp[V] = run;
    return;
  }
  int idx = (bid - 4) * 256 + threadIdx.x;
  #pragma unroll
  for (int t = 0; t < 4; ++t) {
    int sz = bp.N[t] * bp.K[t];
    if (idx < sz) {
      int K = bp.K[t];
      int n = idx / K, k = idx - n * K;
      float v = bp.wp[t][(size_t)k * bp.N[t] + n];
      _Float16 h0 = (_Float16)v;
      float r = (v - (float)h0) * 2048.0f;
      int ks = ((((k >> 3) ^ (n & 7)) << 3) | (k & 7));   // chunk-XOR swizzle
      bp.b0[bp.off[t] + (size_t)n * K + ks] = h0;
      bp.b1[bp.off[t] + (size_t)n * K + ks] = (_Float16)r;
      return;
    }
    idx -= sz;
  }
}

// ---------------------------------------------------------------- K4: fill
__global__ void fill_kernel(CsrParams p) {
  int l = blockIdx.y;
  int k = blockIdx.x * 256 + threadIdx.x;
  if (k < p.nnz[l]) {
    int r = p.row[l][k];
    int pos = atomicAdd(&p.cnt[l][r], 1);
    p.colsout[l][pos] = p.col[l][k];
    p.valsout[l][pos] = p.val[l][k];
  }
}

// ---------------------------------------------------------------- pool (CSR gather, batch-affine, 8ch/thread)
__global__ __launch_bounds__(256) void pool_kernel(
    const float* __restrict__ x,
    const int* __restrict__ rowptr,
    const int* __restrict__ cols,
    const float* __restrict__ vals,
    float* __restrict__ out,
    int Vout, int Vin, int Cin) {
  const int lpr    = Cin >> 3;
  const int lshift = 31 - __clz(lpr);
  const int rpb    = 256 >> lshift;
  const int lr = threadIdx.x >> lshift;
  const int lc = threadIdx.x & (lpr - 1);
  const int b  = blockIdx.x & 7;            // XCD-affine batch
  const int n  = (blockIdx.x >> 3) * rpb + lr;
  const int c8 = lc << 3;
  const float* xb = x + (size_t)b * Vin * Cin + c8;
  const int nu = (lpr >= 64) ? __builtin_amdgcn_readfirstlane(n) : n;
  int j0 = rowptr[nu], j1 = rowptr[nu + 1];
  int cnt = j1 - j0;
  float4 a0 = make_float4(0.f, 0.f, 0.f, 0.f);
  float4 a1 = make_float4(0.f, 0.f, 0.f, 0.f);
  if (cnt > 0) {
    int   cc[4];
    float vv[4];
    #pragma unroll
    for (int k = 0; k < 4; ++k) {
      int jj = j0 + ((k < cnt) ? k : 0);    // in-bounds (cnt>0)
      cc[k] = cols[jj];
      vv[k] = (k < cnt) ? vals[jj] : 0.f;
    }
    #pragma unroll
    for (int k = 0; k < 4; ++k) {
      const float* xr = xb + (size_t)cc[k] * Cin;
      float4 x0 = *(const float4*)xr;
      float4 x1 = *(const float4*)(xr + 4);
      float v = vv[k];
      a0.x = fmaf(v, x0.x, a0.x); a0.y = fmaf(v, x0.y, a0.y);
      a0.z = fmaf(v, x0.z, a0.z); a0.w = fmaf(v, x0.w, a0.w);
      a1.x = fmaf(v, x1.x, a1.x); a1.y = fmaf(v, x1.y, a1.y);
      a1.z = fmaf(v, x1.z, a1.z); a1.w = fmaf(v, x1.w, a1.w);
    }
    for (int j = j0 + 4; j < j1; ++j) {     // rare tail (cnt>4)
      float v = vals[j];
      const float* xr = xb + (size_t)cols[j] * Cin;
      float4 x0 = *(const float4*)xr;
      float4 x1 = *(const float4*)(xr + 4);
      a0.x = fmaf(v, x0.x, a0.x); a0.y = fmaf(v, x0.y, a0.y);
      a0.z = fmaf(v, x0.z, a0.z); a0.w = fmaf(v, x0.w, a0.w);
      a1.x = fmaf(v, x1.x, a1.x); a1.y = fmaf(v, x1.y, a1.y);
      a1.z = fmaf(v, x1.z, a1.z); a1.w = fmaf(v, x1.w, a1.w);
    }
  }
  float* op = &out[((size_t)b * Vout + n) * Cin + c8];
  *(float4*)op = a0;
  *(float4*)(op + 4) = a1;
}

// ---------------------------------------------------------------- dw gather + f16x2 split (batch-affine, 8ch/thread)
// Output A planes PRE-SWIZZLED: chunk c of row m lands at c^(m&7).
__global__ __launch_bounds__(256) void dw_split_kernel(
    const float* __restrict__ xin,
    const int* __restrict__ sidx,
    const float* __restrict__ wd,
    _Float16* __restrict__ a0o,
    _Float16* __restrict__ a1o,
    int Vout, int Cin) {
  const int lpr    = Cin >> 3;
  const int lshift = 31 - __clz(lpr);
  const int rpb    = 256 >> lshift;
  const int lr = threadIdx.x >> lshift;
  const int lc = threadIdx.x & (lpr - 1);
  const int b  = blockIdx.x & 7;
  const int n  = (blockIdx.x >> 3) * rpb + lr;
  const int c8 = lc << 3;
  const float* xb = xin + (size_t)b * Vout * Cin + c8;
  const int nu = (lpr >= 64) ? __builtin_amdgcn_readfirstlane(n) : n;

  int idx[9];
  #pragma unroll
  for (int s = 0; s < 9; ++s) idx[s] = sidx[nu * 9 + s];

  float4 a0 = make_float4(0.f, 0.f, 0.f, 0.f);
  float4 a1 = make_float4(0.f, 0.f, 0.f, 0.f);
  #pragma unroll
  for (int s = 0; s < 9; ++s) {
    const float* xr = xb + (size_t)idx[s] * Cin;
    float4 x0 = *(const float4*)xr;
    float4 x1 = *(const float4*)(xr + 4);
    const float* wr = wd + s * Cin + c8;
    float4 w0 = *(const float4*)wr;
    float4 w1 = *(const float4*)(wr + 4);
    a0.x = fmaf(w0.x, x0.x, a0.x); a0.y = fmaf(w0.y, x0.y, a0.y);
    a0.z = fmaf(w0.z, x0.z, a0.z); a0.w = fmaf(w0.w, x0.w, a0.w);
    a1.x = fmaf(w1.x, x1.x, a1.x); a1.y = fmaf(w1.y, x1.y, a1.y);
    a1.z = fmaf(w1.z, x1.z, a1.z); a1.w = fmaf(w1.w, x1.w, a1.w);
  }

  size_t m = (size_t)b * Vout + n;
  float v[8] = {a0.x, a0.y, a0.z, a0.w, a1.x, a1.y, a1.z, a1.w};
  f16x8 hi, lo;
  #pragma unroll
  for (int i = 0; i < 8; ++i) {
    _Float16 h0 = (_Float16)v[i];
    float r = (v[i] - (float)h0) * 2048.0f;   // exact pow2; lo-plane stays normal
    hi[i] = h0;
    lo[i] = (_Float16)r;
  }
  const int c8s = (lc ^ (n & 7)) << 3;        // swizzled chunk position
  *(f16x8*)&a0o[m * Cin + c8s] = hi;
  *(f16x8*)&a1o[m * Cin + c8s] = lo;
}

// ---------------------------------------------------------------- f16x2-split MFMA GEMM + bias + relu (batch-affine)
// BM=128, BN=64, BK=64; 2x2 waves, wave tile 64x32, mfma 16x16x32.
// K compile-time -> full K-loop unroll (no loop/addr overhead).
// Staging via global_load_lds (16B/lane, linear LDS); operands pre-swizzled
// in global (chunk^(row&7)), reads apply the same XOR. LDS 48KB.
template <int K>
__global__ __launch_bounds__(256) void gemm_f16x2(
    const _Float16* __restrict__ A0, const _Float16* __restrict__ A1,
    const _Float16* __restrict__ Bt0, const _Float16* __restrict__ Bt1,
    const float* __restrict__ bias, float* __restrict__ C,
    int M, int N) {
  __shared__ _Float16 As[2][128 * 64];      // linear; halves index = chunk*8
  __shared__ _Float16 Bs[2][64 * 64];
  const int tid = threadIdx.x;
  const int bx = blockIdx.x;
  const int xr_ = (bx & 7) * (gridDim.x >> 3) + (bx >> 3);   // batch-affine remap
  const int m0 = xr_ * 128, n0 = blockIdx.y * 64;
  const int wid = tid >> 6, lane = tid & 63;
  const int wr = wid >> 1, wc = wid & 1;
  const int lo = lane & 15, hi = lane >> 4;

  // hoist bias loads: latency hides under the K-loop instead of the epilogue
  float bv[2];
  bv[0] = bias[n0 + wc * 32 + 0 * 16 + lo];
  bv[1] = bias[n0 + wc * 32 + 1 * 16 + lo];

  f32x4 accM[4][2], accC[4][2];
  #pragma unroll
  for (int mi = 0; mi < 4; ++mi)
    #pragma unroll
    for (int nj = 0; nj < 2; ++nj) {
      accM[mi][nj] = (f32x4){0.f, 0.f, 0.f, 0.f};
      accC[mi][nj] = (f32x4){0.f, 0.f, 0.f, 0.f};
    }

  const _Float16* gA[2] = {A0, A1};
  const _Float16* gB[2] = {Bt0, Bt1};

  #pragma unroll
  for (int k0 = 0; k0 < K; k0 += 64) {
    #pragma unroll
    for (int p = 0; p < 2; ++p) {
      #pragma unroll
      for (int i = 0; i < 4; ++i) {          // A plane: 1024 16B chunks
        int c = tid + 256 * i;
        int r = c >> 3, k8 = (c & 7) << 3;
        gload_lds16(gA[p] + (size_t)(m0 + r) * K + k0 + k8,
                    &As[p][(c & ~63) * 8]);  // wave-uniform base; HW adds lane*16B
      }
      #pragma unroll
      for (int i = 0; i < 2; ++i) {          // B plane: 512 chunks
        int c = tid + 256 * i;
        int r = c >> 3, k8 = (c & 7) << 3;
        gload_lds16(gB[p] + (size_t)(n0 + r) * K + k0 + k8,
                    &Bs[p][(c & ~63) * 8]);
      }
    }
    __syncthreads();                          // compiler drains vmcnt before barrier
    #pragma unroll
    for (int s = 0; s < 2; ++s) {
      const int cl = s * 4 + hi;              // local chunk 0..7 (kk = cl*8)
      f16x8 af[4][2], bf[2][2];
      #pragma unroll
      for (int mi = 0; mi < 4; ++mi) {
        const int rr = wr * 64 + mi * 16 + lo;
        const int ko = (cl ^ (rr & 7)) << 3;  // un-swizzle on read
        af[mi][0] = *(const f16x8*)&As[0][rr * 64 + ko];
        af[mi][1] = *(const f16x8*)&As[1][rr * 64 + ko];
      }
      #pragma unroll
      for (int nj = 0; nj < 2; ++nj) {
        const int rb = wc * 32 + nj * 16 + lo;
        const int ko = (cl ^ (rb & 7)) << 3;
        bf[nj][0] = *(const f16x8*)&Bs[0][rb * 64 + ko];
        bf[nj][1] = *(const f16x8*)&Bs[1][rb * 64 + ko];
      }
      #pragma unroll
      for (int mi = 0; mi < 4; ++mi)
        #pragma unroll
        for (int nj = 0; nj < 2; ++nj) {
          accM[mi][nj] = __builtin_amdgcn_mfma_f32_16x16x32_f16(
              af[mi][0], bf[nj][0], accM[mi][nj], 0, 0, 0);
          accC[mi][nj] = __builtin_amdgcn_mfma_f32_16x16x32_f16(
              af[mi][0], bf[nj][1], accC[mi][nj], 0, 0, 0);
          accC[mi][nj] = __builtin_amdgcn_mfma_f32_16x16x32_f16(
              af[mi][1], bf[nj][0], accC[mi][nj], 0, 0, 0);
        }
    }
    __syncthreads();
  }

  const float INV = 1.0f / 2048.0f;
  #pragma unroll
  for (int mi = 0; mi < 4; ++mi)
    #pragma unroll
    for (int nj = 0; nj < 2; ++nj) {
      int col = n0 + wc * 32 + nj * 16 + lo;
      #pragma unroll
      for (int r = 0; r < 4; ++r) {
        int row = m0 + wr * 64 + mi * 16 + hi * 4 + r;
        float v = accM[mi][nj][r] + accC[mi][nj][r] * INV + bv[nj];
        v = fmaxf(v, 0.f);
        C[(size_t)row * N + col] = v;
      }
    }
}

// ---------------------------------------------------------------- fused head: dw (Cin=64, lane=channel) + 64x3 proj
// 2 rows per wave: 18 gathers in flight, half the waves.
__global__ __launch_bounds__(256) void head_fused_kernel(
    const float* __restrict__ x,      // [8][8192][64]
    const int* __restrict__ sidx,     // [8192][9]
    const float* __restrict__ wdh,    // [9][64]
    const float* __restrict__ wph,    // [64][3]
    const float* __restrict__ bh,
    float* __restrict__ out) {        // [8][8192][3]
  const int bid  = blockIdx.x;
  const int b    = bid & 7;           // XCD-affine batch
  const int wid  = threadIdx.x >> 6;
  const int lane = threadIdx.x & 63;
  const int n0   = (bid >> 3) * 8 + wid;   // rows n0 and n0+4
  const int n1   = n0 + 4;
  const float* xb = x + (size_t)b * 8192 * 64 + lane;

  int idx0[9], idx1[9];
  #pragma unroll
  for (int s = 0; s < 9; ++s) idx0[s] = sidx[n0 * 9 + s];
  #pragma unroll
  for (int s = 0; s < 9; ++s) idx1[s] = sidx[n1 * 9 + s];

  float acc0 = 0.f, acc1 = 0.f;
  #pragma unroll
  for (int s = 0; s < 9; ++s) {
    float w = wdh[s * 64 + lane];
    acc0 = fmaf(w, xb[(size_t)idx0[s] * 64], acc0);
    acc1 = fmaf(w, xb[(size_t)idx1[s] * 64], acc1);
  }

  float p0 = wph[lane * 3 + 0];
  float p1 = wph[lane * 3 + 1];
  float p2 = wph[lane * 3 + 2];
  float a00 = acc0 * p0, a01 = acc0 * p1, a02 = acc0 * p2;
  float a10 = acc1 * p0, a11 = acc1 * p1, a12 = acc1 * p2;
  for (int off = 32; off > 0; off >>= 1) {
    a00 += __shfl_down(a00, off);
    a01 += __shfl_down(a01, off);
    a02 += __shfl_down(a02, off);
    a10 += __shfl_down(a10, off);
    a11 += __shfl_down(a11, off);
    a12 += __shfl_down(a12, off);
  }
  if (lane == 0) {
    size_t row0 = (size_t)b * 8192 + n0;
    out[row0 * 3 + 0] = a00 + bh[0];
    out[row0 * 3 + 1] = a01 + bh[1];
    out[row0 * 3 + 2] = a02 + bh[2];
    size_t row1 = (size_t)b * 8192 + n1;
    out[row1 * 3 + 0] = a10 + bh[0];
    out[row1 * 3 + 1] = a11 + bh[1];
    out[row1 * 3 + 2] = a12 + bh[2];
  }
}

// ---------------------------------------------------------------- launch
extern "C" void kernel_launch(void* const* d_in, const int* in_sizes, int n_in,
                              void* d_out, int out_size, void* d_ws, size_t ws_size,
                              hipStream_t stream) {
  const float* uv   = (const float*)d_in[0];
  const float* feat = (const float*)d_in[1];
  const float* up   = (const float*)d_in[2];
  const int* sArr[4] = {(const int*)d_in[3], (const int*)d_in[4],
                        (const int*)d_in[5], (const int*)d_in[6]};

  // workspace layout
  const size_t SLAB = 8ull * 2048 * 512;            // 8,388,608 elements
  float* Wf = (float*)d_ws;
  float* S0 = Wf;                                   // fp32 slab (x / gemm out); live < 4.2M floats
  float* S1 = Wf + SLAB;                            // fp32 slab (pool out)
  _Float16* A0 = (_Float16*)(S1 + SLAB);            // dw hi plane (pre-swizzled)
  _Float16* A1 = A0 + SLAB;                         // dw lo plane
  _Float16* Bt0all = (_Float16*)(S0 + 4500000);     // dead upper part of S0
  _Float16* Bt1all = Bt0all + 434176;
  float* xs = (float*)(A1 + SLAB);                  // B*P*512 floats
  int* ib = (int*)(xs + (size_t)B_ * P_ * 512);

  int Vt[4] = {1024, 2048, 4096, 8192};
  int NZ[4] = {3072, 6144, 12288, 24576};
  int* cnt[4]; int* rp[4]; int* co[4]; float* va[4];
  {
    int* pc = ib;
    for (int t = 0; t < 4; ++t) { cnt[t] = pc; pc += Vt[t]; }          // 15360 ints
    for (int t = 0; t < 4; ++t) { rp[t] = pc; pc += Vt[t] + 1; }
    for (int t = 0; t < 4; ++t) { co[t] = pc; pc += NZ[t]; }
    float* pv = (float*)pc;
    for (int t = 0; t < 4; ++t) { va[t] = pv; pv += NZ[t]; }
  }

  CsrParams cp;
  for (int t = 0; t < 4; ++t) {
    int i = 3 - t;
    cp.row[t] = (const int*)d_in[7 + 3 * i];
    cp.col[t] = (const int*)d_in[8 + 3 * i];
    cp.val[t] = (const float*)d_in[9 + 3 * i];
    cp.cnt[t] = cnt[t]; cp.rowptr[t] = rp[t];
    cp.colsout[t] = co[t]; cp.valsout[t] = va[t];
    cp.nnz[t] = NZ[t]; cp.V[t] = Vt[t];
  }

  struct Stg { int Vin, Vout, Cin, Cout; const int* s; const float *wd, *wp, *bias; };
  Stg st[4] = {
    {512, 1024, 512, 512, sArr[3], (const float*)d_in[19], (const float*)d_in[20], (const float*)d_in[21]},
    {1024, 2048, 512, 256, sArr[2], (const float*)d_in[22], (const float*)d_in[23], (const float*)d_in[24]},
    {2048, 4096, 256, 128, sArr[1], (const float*)d_in[25], (const float*)d_in[26], (const float*)d_in[27]},
    {4096, 8192, 128, 64, sArr[0], (const float*)d_in[28], (const float*)d_in[29], (const float*)d_in[30]},
  };

  BsplitParams bp;
  int boff = 0;
  for (int t = 0; t < 4; ++t) {
    bp.wp[t] = st[t].wp;
    bp.K[t] = st[t].Cin; bp.N[t] = st[t].Cout;
    bp.off[t] = boff;
    boff += st[t].Cin * st[t].Cout;           // 434176 total
  }
  bp.b0 = Bt0all; bp.b1 = Bt1all;
  int bsplit_blocks = (boff + 255) / 256;     // 1696

  // front matter: 4 merged kernels (3 independent chains interleaved)
  k1_zero_sample<<<60 + B_ * P_, 256, 0, stream>>>(ib, 15360, uv, feat, xs);
  k2_count_upsample<<<384 + 512 * B_, 256, 0, stream>>>(cp, up, xs, S0);
  k3_scan_bsplit<<<4 + bsplit_blocks, 256, 0, stream>>>(cp, bp);
  fill_kernel<<<dim3(96, 4), 256, 0, stream>>>(cp);

  for (int t = 0; t < 4; ++t) {
    int rpb = 2048 / st[t].Cin;               // rows/block at 8 ch/thread
    pool_kernel<<<8 * (st[t].Vout / rpb), 256, 0, stream>>>(
        S0, rp[t], co[t], va[t], S1, st[t].Vout, st[t].Vin, st[t].Cin);
    dw_split_kernel<<<8 * (st[t].Vout / rpb), 256, 0, stream>>>(
        S1, st[t].s, st[t].wd, A0, A1, st[t].Vout, st[t].Cin);
    int M = B_ * st[t].Vout;
    dim3 gg(M / 128, st[t].Cout / 64);
    const _Float16* Bt0 = Bt0all + bp.off[t];
    const _Float16* Bt1 = Bt1all + bp.off[t];
    if (st[t].Cin == 512)
      gemm_f16x2<512><<<gg, 256, 0, stream>>>(A0, A1, Bt0, Bt1, st[t].bias, S0, M, st[t].Cout);
    else if (st[t].Cin == 256)
      gemm_f16x2<256><<<gg, 256, 0, stream>>>(A0, A1, Bt0, Bt1, st[t].bias, S0, M, st[t].Cout);
    else
      gemm_f16x2<128><<<gg, 256, 0, stream>>>(A0, A1, Bt0, Bt1, st[t].bias, S0, M, st[t].Cout);
  }

  // fused head: dw (K=64) + 64x3 projection, 2 rows/wave
  head_fused_kernel<<<8 * (8192 / 8), 256, 0, stream>>>(
      S0, sArr[0], (const float*)d_in[31], (const float*)d_in[32],
      (const float*)d_in[33], (float*)d_out);
}